// Round 27
// baseline (557.460 us; speedup 1.0000x reference)
//
#include <hip/hip_runtime.h>
#include <stdint.h>

typedef __attribute__((ext_vector_type(8))) short short8;
typedef __attribute__((ext_vector_type(4))) float f32x4;
typedef __attribute__((ext_vector_type(2))) float f32x2;
typedef unsigned short u16;
typedef uint32_t u32;
typedef unsigned long long u64;

// ---------------- threefry2x32-20 (JAX-compatible) ----------------
__host__ __device__ static inline void threefry(u32 k0, u32 k1, u32 x0, u32 x1,
                                                u32* o0, u32* o1) {
  u32 ks2 = k0 ^ k1 ^ 0x1BD11BDAu;
  x0 += k0; x1 += k1;
#define TF_RR(r) { x0 += x1; x1 = (x1 << (r)) | (x1 >> (32 - (r))); x1 ^= x0; }
  TF_RR(13) TF_RR(15) TF_RR(26) TF_RR(6)
  x0 += k1;  x1 += ks2 + 1u;
  TF_RR(17) TF_RR(29) TF_RR(16) TF_RR(24)
  x0 += ks2; x1 += k0 + 2u;
  TF_RR(13) TF_RR(15) TF_RR(26) TF_RR(6)
  x0 += k0;  x1 += k1 + 3u;
  TF_RR(17) TF_RR(29) TF_RR(16) TF_RR(24)
  x0 += k1;  x1 += ks2 + 4u;
  TF_RR(13) TF_RR(15) TF_RR(26) TF_RR(6)
  x0 += ks2; x1 += k0 + 5u;
#undef TF_RR
  *o0 = x0; *o1 = x1;
}

__device__ static inline float bf2f(u16 u) {
  union { u32 i; float f; } v; v.i = ((u32)u) << 16; return v.f;
}
__device__ static inline u16 f2bf(float f) {
  union { float f; u32 i; } v; v.f = f;
  u32 x = v.i;
  return (u16)((x + 0x7FFFu + ((x >> 16) & 1u)) >> 16);
}
__device__ static inline float lo_bf(u32 w) {
  union { u32 i; float f; } v; v.i = w << 16; return v.f;
}
__device__ static inline float hi_bf(u32 w) {
  union { u32 i; float f; } v; v.i = w & 0xFFFF0000u; return v.f;
}
__device__ static inline bool is_f32(const u32* ng) { return ng[0] == 0x3F800000u; }

// async global->LDS, 16B per lane
typedef const uint32_t __attribute__((address_space(1)))* gas_ptr;
typedef uint32_t __attribute__((address_space(3)))* las_ptr;
__device__ static inline void gld16(const u16* g, u16* l) {
  __builtin_amdgcn_global_load_lds((gas_ptr)(const void*)g, (las_ptr)(void*)l, 16, 0, 0);
}

#define MASK_HALF 9834496u

// ---------------- fused dropkey mask gen -> per-row 7-word records ----------------
__global__ __launch_bounds__(256) void mask_gen2(u32* __restrict__ MSK2, u32 k0, u32 k1) {
  int t = blockIdx.x * 256 + threadIdx.x;
  if (t >= 351232) return;  // 16 bh-halves * 3136 rows * 7 words
  int w = t % 7;
  int rowbh = t / 7;  // bh*3136 + row, bh in [0,16)
  u32 base = (u32)rowbh * 196u + (u32)w * 32u;
  int kmax = 196 - w * 32;
  if (kmax > 32) kmax = 32;
  u32 bits0 = 0, bits1 = 0;
  for (int j = 0; j < kmax; j++) {
    u32 o0, o1;
    threefry(k0, k1, base + (u32)j, base + (u32)j + MASK_HALF, &o0, &o1);
    union { u32 u; float f; } u0, u1;
    u0.u = (o0 >> 9) | 0x3F800000u;
    u1.u = (o1 >> 9) | 0x3F800000u;
    if (u0.f - 1.0f < 0.1f) bits0 |= (1u << j);
    if (u1.f - 1.0f < 0.1f) bits1 |= (1u << j);
  }
  MSK2[(size_t)rowbh * 7 + w] = bits0;
  MSK2[(size_t)(rowbh + 50176) * 7 + w] = bits1;  // bh+16 half
}

// ---------------- param conversion into bf16 arena + VT zeroing ----------------
// sr_w (t==6) is stored with PERMUTED K: dst k' = ij*128+c  <-  src k = c*16+ij.
struct PtrTab { const void* p[20]; };
#define ARENA_N 963968
#define VT_WORDS 229376

__global__ __launch_bounds__(256) void convert_params(PtrTab tab, u16* __restrict__ arena,
                                                      u32* __restrict__ VT) {
  const int cum[21] = {0, 32768, 32896, 33152, 33408, 66176, 131712, 656000, 656256,
                       656512, 656768, 689536, 689792, 690048, 690304, 821376, 822400,
                       831616, 832640, 963712, 963968};
  int idx = blockIdx.x * 256 + threadIdx.x;
  if (idx >= ARENA_N) {
    int v = idx - ARENA_N;
    if (v < VT_WORDS) VT[v] = 0;
    return;
  }
  bool f32m = (((const u32*)tab.p[2])[0] == 0x3F800000u);
  int t = 0;
  while (idx >= cum[t + 1]) t++;
  int local = idx - cum[t];
  if (t == 16) {  // dw_w transposed to [blk][wi][c]
    int blk = local / 4608, r = local - blk * 4608;
    int wi = r >> 9, c = r & 511;
    local = blk * 4608 + c * 9 + wi;
  } else if (t == 6) {  // sr_w: dst (blk, o, k'=ij*128+c) <- src (blk, o, c*16+ij)
    int blk = local / 262144, r = local - blk * 262144;
    int o = r >> 11, kp = r & 2047;
    int ij = kp >> 7, c = kp & 127;
    local = blk * 262144 + o * 2048 + c * 16 + ij;
  }
  u16 v;
  if (f32m) v = f2bf(((const float*)tab.p[t])[local]);
  else      v = ((const u16*)tab.p[t])[local];
  arena[idx] = v;
}

// ---------------- input transpose ----------------
__global__ __launch_bounds__(256) void transpose_in(const void* __restrict__ Xin,
                                                    const u32* __restrict__ ng,
                                                    u16* __restrict__ Xt) {
  bool f32m = is_f32(ng);
  __shared__ u16 tile[64][65];
  int n0 = blockIdx.x * 64, c0 = blockIdx.y * 64, b = blockIdx.z;
  int tx = threadIdx.x & 63, ty = threadIdx.x >> 6;
  if (f32m) {
    const float* src = (const float*)Xin + (size_t)b * 256 * 3136;
#pragma unroll
    for (int i = 0; i < 16; i++) {
      int cl = i * 4 + ty;
      tile[cl][tx] = f2bf(src[(size_t)(c0 + cl) * 3136 + n0 + tx]);
    }
  } else {
    const u16* src = (const u16*)Xin + (size_t)b * 256 * 3136;
#pragma unroll
    for (int i = 0; i < 16; i++) {
      int cl = i * 4 + ty;
      tile[cl][tx] = src[(size_t)(c0 + cl) * 3136 + n0 + tx];
    }
  }
  __syncthreads();
  u16* dst = Xt + (size_t)b * 3136 * 256;
#pragma unroll
  for (int i = 0; i < 16; i++) {
    int nl = i * 4 + ty;
    dst[(size_t)(n0 + nl) * 256 + c0 + tx] = tile[tx][nl];
  }
}

// ---------------- output transpose: X bf16 [b][3136][128] -> out [b][128][3136] --------
__global__ __launch_bounds__(256) void transpose_out(const u16* __restrict__ X,
                                                     const u32* __restrict__ ng,
                                                     void* __restrict__ Out) {
  bool f32m = is_f32(ng);
  __shared__ u16 tile[64][65];
  int n0 = blockIdx.x * 64, d0 = blockIdx.y * 64, b = blockIdx.z;
  int tx = threadIdx.x & 63, ty = threadIdx.x >> 6;
#pragma unroll
  for (int i = 0; i < 16; i++) {
    int nl = i * 4 + ty;
    tile[nl][tx] = X[((size_t)b * 3136 + n0 + nl) * 128 + d0 + tx];
  }
  __syncthreads();
#pragma unroll
  for (int i = 0; i < 16; i++) {
    int dl = i * 4 + ty;
    size_t o = ((size_t)b * 128 + d0 + dl) * 3136 + n0 + tx;
    if (f32m) ((float*)Out)[o] = bf2f(tile[tx][dl]);
    else      ((u16*)Out)[o]   = tile[tx][dl];
  }
}

// ---------------- tiled MFMA GEMM (m-tile = blockIdx.x, n-tile = blockIdx.y) -----------
__global__ __launch_bounds__(256) __attribute__((amdgpu_waves_per_eu(2, 4)))
void gemm_tiled(const u16* __restrict__ A,
                const u16* __restrict__ W,
                const u16* __restrict__ bias,
                u16* __restrict__ outB,
                u16* __restrict__ outVT,
                int M, int N, int K, int mode) {
  __shared__ __align__(16) u16 smem[17408];  // staging 32KB / C-tile [128][136]
  u16* AlsP = smem;
  u16* BlsP = smem + 8192;
  int n0 = blockIdx.y * 128, m0 = blockIdx.x * 128;
  int tid = threadIdx.x, wv = tid >> 6, lane = tid & 63;
  int wr = wv >> 1, wc = wv & 1;
  int l15 = lane & 15, hh = lane >> 4, lk = hh * 8;
  int srow = wv * 32 + (lane >> 2);
  int scol = (lane & 3) * 8;

  f32x4 acc[4][4];
#pragma unroll
  for (int m = 0; m < 4; m++)
#pragma unroll
    for (int n = 0; n < 4; n++) acc[m][n] = (f32x4){0.f, 0.f, 0.f, 0.f};

#define STAGE(buf, k0)                                                          \
  {                                                                             \
    _Pragma("unroll") for (int i = 0; i < 2; i++) {                             \
      int ar = m0 + srow + i * 16;                                              \
      if (ar >= M) ar = M - 1;                                                  \
      gld16(A + (size_t)ar * K + (k0) + scol,                                   \
            AlsP + (buf) * 4096 + (wv * 32 + i * 16) * 32);                     \
      int br = n0 + srow + i * 16;                                              \
      gld16(W + (size_t)br * K + (k0) + scol,                                   \
            BlsP + (buf) * 4096 + (wv * 32 + i * 16) * 32);                     \
    }                                                                           \
  }

  int nt = K >> 5;
  STAGE(0, 0);
  int cur = 0;
  for (int t = 0; t < nt; t++) {
    __syncthreads();
    if (t + 1 < nt) STAGE(cur ^ 1, (t + 1) * 32);
    short8 af[4], bf[4];
#pragma unroll
    for (int m = 0; m < 4; m++)
      af[m] = *(const short8*)(AlsP + cur * 4096 + (wr * 64 + m * 16 + l15) * 32 + lk);
#pragma unroll
    for (int n = 0; n < 4; n++)
      bf[n] = *(const short8*)(BlsP + cur * 4096 + (wc * 64 + n * 16 + l15) * 32 + lk);
#pragma unroll
    for (int m = 0; m < 4; m++)
#pragma unroll
      for (int n = 0; n < 4; n++)
        acc[m][n] = __builtin_amdgcn_mfma_f32_16x16x32_bf16(af[m], bf[n], acc[m][n], 0, 0, 0);
    cur ^= 1;
  }
#undef STAGE

  if (mode == 0) {
    __syncthreads();
#pragma unroll
    for (int n = 0; n < 4; n++) {
      int col = wc * 64 + n * 16 + l15;
      float bv = bias ? bf2f(bias[n0 + col]) : 0.0f;
#pragma unroll
      for (int m = 0; m < 4; m++) {
        int rbase = wr * 64 + m * 16 + hh * 4;
#pragma unroll
        for (int r = 0; r < 4; r++)
          smem[(rbase + r) * 136 + col] = f2bf(acc[m][n][r] + bv);
      }
    }
    __syncthreads();
#pragma unroll
    for (int p = 0; p < 8; p++) {
      int row = p * 16 + (tid >> 4);
      int colb = (tid & 15) * 8;
      int grow = m0 + row;
      if (grow < M) {
        short8 v = *(const short8*)&smem[row * 136 + colb];
        *(short8*)(outB + (size_t)grow * N + n0 + colb) = v;
      }
    }
    return;
  }

  // mode 3 (kv)
#pragma unroll
  for (int n = 0; n < 4; n++) {
    int col = n0 + wc * 64 + n * 16 + l15;
#pragma unroll
    for (int m = 0; m < 4; m++) {
      int rbase = m0 + wr * 64 + m * 16 + hh * 4;
#pragma unroll
      for (int r = 0; r < 4; r++) {
        int row = rbase + r;
        if (row < M) {
          float v = acc[m][n][r];
          if (col < 128) outB[(size_t)row * 128 + col] = f2bf(v);
          else {
            int hd = (col - 128) >> 6, d = (col - 128) & 63;
            int b = row / 196, key = row - b * 196;
            outVT[(size_t)((b * 2 + hd) * 64 + d) * 224 + key] = f2bf(v);
          }
        }
      }
    }
  }
}

// ---------------- barrier-free N=128 GEMM (concat/proj/fc2[,+q]) -- 784 blocks ---------
// Each wave owns 16 complete rows x 128 cols (acc[8]). A and W fragments load DIRECTLY
// global->VGPR (A L3-hot from producer; W L2-resident, shared by all blocks). No LDS
// staging, no __syncthreads anywhere: waves are independent latency chains. LN is
// per-row -> wave-local shfl reduce. H/Q stores coalesce through a wave-PRIVATE smem
// region using in-wave LDS ordering (attn-proven pattern). GEMM K-order identical to
// the previous version -> Xb bit-identical; only LN-stat summation order changes (LSB).
__global__ __launch_bounds__(256) __attribute__((amdgpu_waves_per_eu(2, 4)))
void gemm_n128(const u16* __restrict__ A,
               const u16* __restrict__ W,
               const u16* __restrict__ bias,
               u16* __restrict__ Xb,
               u16* __restrict__ outB,
               const u16* __restrict__ lnG,
               const u16* __restrict__ lnB,
               u16* __restrict__ outH,
               const u16* __restrict__ qW,
               u16* __restrict__ outQ,
               int M, int K, int mode) {
  (void)outB; (void)M;
  __shared__ __align__(16) u16 smem[8704];  // 4 waves x [16][136] private regions
  int tid = threadIdx.x, wv = tid >> 6, lane = tid & 63;
  int l15 = lane & 15, h = lane >> 4, lk = h * 8;
  int mw = blockIdx.y * 64 + wv * 16;  // wave's first output row
  u16* ws = smem + wv * 2176;

  f32x4 acc[8];
#pragma unroll
  for (int n = 0; n < 8; n++) acc[n] = (f32x4){0.f, 0.f, 0.f, 0.f};

  const u16* arow = A + (size_t)(mw + l15) * K + lk;
  int nt = K >> 5;
  for (int t = 0; t < nt; t++) {
    short8 af = *(const short8*)(arow + t * 32);
    short8 bf[8];
#pragma unroll
    for (int n = 0; n < 8; n++)
      bf[n] = *(const short8*)(W + (size_t)(n * 16 + l15) * K + t * 32 + lk);
#pragma unroll
    for (int n = 0; n < 8; n++)
      acc[n] = __builtin_amdgcn_mfma_f32_16x16x32_bf16(af, bf[n], acc[n], 0, 0, 0);
  }

  if (mode == 2) {
#pragma unroll
    for (int n = 0; n < 8; n++) {
      int col = n * 16 + l15;
      float bv = bias ? bf2f(bias[col]) : 0.0f;
#pragma unroll
      for (int r = 0; r < 4; r++) {
        size_t idx = (size_t)(mw + h * 4 + r) * 128 + col;
        Xb[idx] = f2bf(bf2f(Xb[idx]) + acc[n][r] + bv);
      }
    }
    return;
  }

  // modes 4/5: residual RMW + per-row wave-local LayerNorm -> outH (+ optional q)
#pragma unroll
  for (int n = 0; n < 8; n++) {
    int col = n * 16 + l15;
    float bv = bias ? bf2f(bias[col]) : 0.0f;
#pragma unroll
    for (int r = 0; r < 4; r++) {
      size_t idx = (size_t)(mw + h * 4 + r) * 128 + col;
      float v = acc[n][r] + bv;
      if (mode == 5) v += bf2f(Xb[idx]);
      acc[n][r] = v;
      Xb[idx] = f2bf(v);
    }
  }
#pragma unroll
  for (int r = 0; r < 4; r++) {
    float a = 0.f, b = 0.f;
#pragma unroll
    for (int n = 0; n < 8; n++) {
      a += acc[n][r];
      b += acc[n][r] * acc[n][r];
    }
#pragma unroll
    for (int d = 1; d < 16; d <<= 1) {
      a += __shfl_xor(a, d);
      b += __shfl_xor(b, d);
    }
    float mean = a * 0.0078125f;
    float var = b * 0.0078125f - mean * mean;
    float inv = 1.0f / sqrtf(var + 1e-5f);
#pragma unroll
    for (int n = 0; n < 8; n++) {
      int col = n * 16 + l15;
      ws[(h * 4 + r) * 136 + col] =
          f2bf((acc[n][r] - mean) * inv * bf2f(lnG[col]) + bf2f(lnB[col]));
    }
  }
  // coalesced H store from private region (in-wave LDS write->read ordering)
#pragma unroll
  for (int p = 0; p < 4; p++) {
    int row = p * 4 + h;
    int colb = l15 * 8;
    short8 v = *(const short8*)&ws[row * 136 + colb];
    *(short8*)(outH + (size_t)(mw + row) * 128 + colb) = v;
  }

  if (qW) {
    // fused q-projection: wave's 16 rows of Q = H_rows @ qW^T, A-frags from private smem
    f32x4 qa[8];
#pragma unroll
    for (int n = 0; n < 8; n++) qa[n] = (f32x4){0.f, 0.f, 0.f, 0.f};
#pragma unroll
    for (int kc = 0; kc < 4; kc++) {
      short8 aq = *(const short8*)&ws[l15 * 136 + kc * 32 + lk];
      short8 bq[8];
#pragma unroll
      for (int n = 0; n < 8; n++)
        bq[n] = *(const short8*)(qW + (size_t)(n * 16 + l15) * 128 + kc * 32 + lk);
#pragma unroll
      for (int n = 0; n < 8; n++)
        qa[n] = __builtin_amdgcn_mfma_f32_16x16x32_bf16(aq, bq[n], qa[n], 0, 0, 0);
    }
    // overwrite private region (all aq reads completed in program order)
#pragma unroll
    for (int n = 0; n < 8; n++)
#pragma unroll
      for (int r = 0; r < 4; r++)
        ws[(h * 4 + r) * 136 + n * 16 + l15] = f2bf(qa[n][r]);
#pragma unroll
    for (int p = 0; p < 4; p++) {
      int row = p * 4 + h;
      int colb = l15 * 8;
      short8 v = *(const short8*)&ws[row * 136 + colb];
      *(short8*)(outQ + (size_t)(mw + row) * 128 + colb) = v;
    }
  }
}

// ---------------- split-K GEMM for SR conv, direct-from-H gather (no im2col) -----------
// K-order k' = ij*128 + c; A element (row=(b,ph,pw), k') = H[(b*3136+(4ph+i)*56+4pw+j)*128+c]
__global__ __launch_bounds__(256) void gemm_splitk(const u16* __restrict__ Hsrc,
                                                   const u16* __restrict__ W,
                                                   float* __restrict__ PS,
                                                   int M, int N, int K) {
  __shared__ __align__(16) u16 Als[2][4096];
  __shared__ __align__(16) u16 Bls[2][4096];
  int n0 = blockIdx.x * 128, m0 = blockIdx.y * 128, ks = blockIdx.z;
  int tid = threadIdx.x, wv = tid >> 6, lane = tid & 63;
  int wr = wv >> 1, wc = wv & 1;
  int l15 = lane & 15, lk = (lane >> 4) * 8;
  int srow = wv * 32 + (lane >> 2);
  int scol = (lane & 3) * 8;

  f32x4 acc[4][4];
#pragma unroll
  for (int m = 0; m < 4; m++)
#pragma unroll
    for (int n = 0; n < 4; n++) acc[m][n] = (f32x4){0.f, 0.f, 0.f, 0.f};

#define STAGE(buf, k0)                                                          \
  {                                                                             \
    _Pragma("unroll") for (int i = 0; i < 2; i++) {                             \
      int ar = m0 + srow + i * 16;                                              \
      if (ar >= M) ar = M - 1;                                                  \
      int bb = ar / 196, pp = ar - bb * 196;                                    \
      int ph = pp / 14, pw = pp - ph * 14;                                      \
      int kk = (k0) + scol;                                                     \
      int ij = kk >> 7, c = kk & 127;                                           \
      int n2 = (4 * ph + (ij >> 2)) * 56 + 4 * pw + (ij & 3);                   \
      gld16(Hsrc + ((size_t)(bb * 3136 + n2)) * 128 + c,                        \
            &Als[buf][(wv * 32 + i * 16) * 32]);                                \
      int br = n0 + srow + i * 16;                                              \
      gld16(W + (size_t)br * K + (k0) + scol,                                   \
            &Bls[buf][(wv * 32 + i * 16) * 32]);                                \
    }                                                                           \
  }

  int kbeg = ks * 128;
  STAGE(0, kbeg);
  int cur = 0;
  for (int t = 0; t < 4; t++) {
    __syncthreads();
    if (t + 1 < 4) STAGE(cur ^ 1, kbeg + (t + 1) * 32);
    short8 af[4], bf[4];
#pragma unroll
    for (int m = 0; m < 4; m++)
      af[m] = *(const short8*)(&Als[cur][(wr * 64 + m * 16 + l15) * 32 + lk]);
#pragma unroll
    for (int n = 0; n < 4; n++)
      bf[n] = *(const short8*)(&Bls[cur][(wc * 64 + n * 16 + l15) * 32 + lk]);
#pragma unroll
    for (int m = 0; m < 4; m++)
#pragma unroll
      for (int n = 0; n < 4; n++)
        acc[m][n] = __builtin_amdgcn_mfma_f32_16x16x32_bf16(af[m], bf[n], acc[m][n], 0, 0, 0);
    cur ^= 1;
  }
#undef STAGE

  float* myPS = PS + (size_t)ks * M * N;
#pragma unroll
  for (int n = 0; n < 4; n++) {
    int col = n0 + wc * 64 + n * 16 + l15;
#pragma unroll
    for (int m = 0; m < 4; m++) {
      int rbase = m0 + wr * 64 + m * 16 + (lane >> 4) * 4;
#pragma unroll
      for (int r = 0; r < 4; r++) {
        int row = rbase + r;
        if (row < M) myPS[(size_t)row * N + col] = acc[m][n][r];
      }
    }
  }
}

// ---------------- fused split-K reduce + srn LayerNorm -> XSN bf16 ----------------
__global__ __launch_bounds__(256) void splitk_reduce_ln(const float* __restrict__ PS,
                                                        const u16* __restrict__ bias,
                                                        const u16* __restrict__ G,
                                                        const u16* __restrict__ Bi,
                                                        u16* __restrict__ XSN) {
  __shared__ float red[4][2];
  int tid = threadIdx.x;
  int row = blockIdx.x * 2 + (tid >> 7);
  int col = tid & 127;
  int t = row * 128 + col;
  float s = bf2f(bias[col]);
#pragma unroll
  for (int k = 0; k < 16; k++) s += PS[(size_t)k * 401408 + t];
  float s1 = s, s2 = s * s;
#pragma unroll
  for (int d = 1; d < 64; d <<= 1) {
    s1 += __shfl_xor(s1, d);
    s2 += __shfl_xor(s2, d);
  }
  int wv = tid >> 6;
  if ((tid & 63) == 0) { red[wv][0] = s1; red[wv][1] = s2; }
  __syncthreads();
  int other = wv ^ 1;
  float t1 = red[wv][0] + red[other][0];
  float t2 = red[wv][1] + red[other][1];
  float mean = t1 * 0.0078125f;
  float var = t2 * 0.0078125f - mean * mean;
  float inv = 1.0f / sqrtf(var + 1e-5f);
  XSN[t] = f2bf((s - mean) * inv * bf2f(G[col]) + bf2f(Bi[col]));
}

// ---------------- fused SR attention v8: K staged in LDS (padded), v5 softmax -----------
__global__ __launch_bounds__(256) __attribute__((amdgpu_waves_per_eu(2, 4)))
void attn_kernel(const u16* __restrict__ Q,
                 const u16* __restrict__ Kb,
                 const u16* __restrict__ VT,
                 const u32* __restrict__ M2,
                 u16* __restrict__ O) {
  __shared__ __align__(16) u16 smA[14848];  // K [196][68] (13328) / P [64][232] (14848)
  int t = blockIdx.x;
  int tp = (t & 7) * 196 + (t >> 3);  // XCD-contiguous bh spans
  int bh = tp / 49, qt = tp - bh * 49;
  int b = bh >> 1, hd = bh & 1;
  int q0 = qt * 64;
  int tid = threadIdx.x;

  int wv = tid >> 6, lane = tid & 63;
  int l15 = lane & 15, h = lane >> 4, lk = h * 8;

  {
    const u16* ksrc = Kb + (size_t)b * 196 * 128 + hd * 64;
    for (int idx = tid; idx < 1568; idx += 256) {
      int row = idx >> 3, ch = idx & 7;
      short8 v = *(const short8*)(ksrc + (size_t)row * 128 + ch * 8);
      *(short8*)&smA[row * 68 + ch * 8] = v;
    }
  }

  const u16* qp = Q + ((size_t)(b * 3136 + q0 + wv * 16 + l15) * 128) + hd * 64 + lk;
  short8 aq0 = *(const short8*)(qp);
  short8 aq1 = *(const short8*)(qp + 32);
  int rowg = q0 + wv * 16 + h * 4;

  u32 mwv[4][7];
  const u32* mwbase = M2 + (size_t)(bh * 3136 + rowg) * 7;
#pragma unroll
  for (int r = 0; r < 4; r++)
#pragma unroll
    for (int w = 0; w < 7; w++) mwv[r][w] = mwbase[r * 7 + w];

  __syncthreads();  // K staged

  float sarr[13][4];
#pragma unroll
  for (int cc = 0; cc < 13; cc++) {
    int key = cc * 16 + l15;
    int keyc = key > 195 ? 195 : key;
    short8 kb0 = *(const short8*)&smA[keyc * 68 + lk];
    short8 kb1 = *(const short8*)&smA[keyc * 68 + 32 + lk];
    f32x4 s = {0.f, 0.f, 0.f, 0.f};
    s = __builtin_amdgcn_mfma_f32_16x16x32_bf16(aq0, kb0, s, 0, 0, 0);
    s = __builtin_amdgcn_mfma_f32_16x16x32_bf16(aq1, kb1, s, 0, 0, 0);
#pragma unroll
    for (int r = 0; r < 4; r++) sarr[cc][r] = s[r] * 0.125f;
  }

#pragma unroll
  for (int cc = 0; cc < 13; cc++) {
    bool keyok = (cc * 16 + l15) < 196;
    int pos = (cc & 3) * 16 + l15;
#pragma unroll
    for (int r = 0; r < 4; r++) {
      u64 mm = (cc < 4) ? ((u64)mwv[r][0] | ((u64)mwv[r][1] << 32))
             : (cc < 8) ? ((u64)mwv[r][2] | ((u64)mwv[r][3] << 32))
             : (cc < 12) ? ((u64)mwv[r][4] | ((u64)mwv[r][5] << 32))
                         : ((u64)mwv[r][6]);
      bool drop = (mm >> pos) & 1ull;
      if (!keyok || drop) sarr[cc][r] = -3.0e38f;
    }
  }

  float mx[4] = {sarr[0][0], sarr[0][1], sarr[0][2], sarr[0][3]};
#pragma unroll
  for (int cc = 1; cc < 13; cc++)
#pragma unroll
    for (int r = 0; r < 4; r++) mx[r] = fmaxf(mx[r], sarr[cc][r]);
#pragma unroll
  for (int d = 1; d < 16; d <<= 1)
#pragma unroll
    for (int r = 0; r < 4; r++) mx[r] = fmaxf(mx[r], __shfl_xor(mx[r], d));
  float sm[4] = {0.f, 0.f, 0.f, 0.f};
#pragma unroll
  for (int cc = 0; cc < 13; cc++)
#pragma unroll
    for (int r = 0; r < 4; r++) {
      float p = __expf(sarr[cc][r] - mx[r]);
      sarr[cc][r] = p;
      sm[r] += p;
    }
#pragma unroll
  for (int d = 1; d < 16; d <<= 1)
#pragma unroll
    for (int r = 0; r < 4; r++) sm[r] += __shfl_xor(sm[r], d);
  float inv[4];
#pragma unroll
  for (int r = 0; r < 4; r++)
    asm("v_rcp_f32 %0, %1" : "=v"(inv[r]) : "v"(sm[r]));

  __syncthreads();  // K region -> P

#pragma unroll
  for (int cc = 0; cc < 13; cc++)
#pragma unroll
    for (int r = 0; r < 4; r++)
      smA[(wv * 16 + h * 4 + r) * 232 + cc * 16 + l15] = f2bf(sarr[cc][r] * inv[r]);
#pragma unroll
  for (int rj = 0; rj < 4; rj++) smA[(wv * 16 + l15) * 232 + 208 + h * 4 + rj] = 0;

  const u16* vbase = VT + (size_t)(bh * 64) * 224;
  short8 vw[4];
#pragma unroll
  for (int i = 0; i < 4; i++) {
    vw[i] = *(const short8*)(vbase + (size_t)(0 * 16 + l15) * 224 + i * 32 + lk);
  }
#pragma unroll
  for (int dc = 0; dc < 4; dc++) {
    f32x4 oa = {0.f, 0.f, 0.f, 0.f};
#pragma unroll
    for (int kc = 0; kc < 7; kc++) {
      int i = dc * 7 + kc;
      short8 bv = vw[i & 3];
      if (i + 4 < 28) {
        int i2 = i + 4;
        int dc2 = i2 / 7, kc2 = i2 - dc2 * 7;
        vw[i & 3] =
            *(const short8*)(vbase + (size_t)(dc2 * 16 + l15) * 224 + kc2 * 32 + lk);
      }
      short8 a = *(const short8*)&smA[(wv * 16 + l15) * 232 + kc * 32 + lk];
      oa = __builtin_amdgcn_mfma_f32_16x16x32_bf16(a, bv, oa, 0, 0, 0);
    }
#pragma unroll
    for (int r = 0; r < 4; r++) {
      O[((size_t)(b * 3136 + rowg + r) * 128) + hd * 64 + dc * 16 + l15] = f2bf(oa[r]);
    }
  }
}

// ---------------- depthwise 3x3 + bias + exp2-sigmoid GELU, cvt_pk output ---------------
__global__ __launch_bounds__(256) __attribute__((amdgpu_waves_per_eu(2, 4)))
void dwconv_gelu(const u16* __restrict__ H2,
                 const u16* __restrict__ Wdw,
                 const u16* __restrict__ Bdw,
                 u16* __restrict__ Out) {
  int tid = threadIdx.x;
  int wv = tid >> 6, lane = tid & 63;
  int sb = blockIdx.x;                          // 3136 blocks
  int wg = (sb & 7) * 392 + (sb >> 3);          // XCD-contiguous remap
  int strip = wg * 4 + wv;                      // < 12544
  int bb = strip / 784;
  int s = strip - bb * 784;
  int y = s / 14, x0 = (s - y * 14) * 4;
  int c0 = lane * 8;

  f32x2 wf[9][4];
#pragma unroll
  for (int t9 = 0; t9 < 9; t9++) {
    short8 w8 = *(const short8*)(Wdw + t9 * 512 + c0);
#pragma unroll
    for (int p = 0; p < 4; p++) {
      u32 w = ((const u32*)&w8)[p];
      wf[t9][p] = (f32x2){lo_bf(w), hi_bf(w)};
    }
  }
  f32x2 acc[4][4];
  {
    short8 b8 = *(const short8*)(Bdw + c0);
#pragma unroll
    for (int p = 0; p < 4; p++) {
      u32 w = ((const u32*)&b8)[p];
      f32x2 bv = {lo_bf(w), hi_bf(w)};
#pragma unroll
      for (int q = 0; q < 4; q++) acc[q][p] = bv;
    }
  }

  const u16* base = H2 + ((size_t)bb * 3136) * 512 + c0;
#pragma unroll
  for (int di = -1; di <= 1; di++) {
    int y2 = y + di;
    if (y2 < 0 || y2 >= 56) continue;
    const u16* rowp = base + (size_t)(y2 * 56) * 512;
#pragma unroll
    for (int j = 0; j < 6; j++) {
      int c = x0 - 1 + j;
      if (c < 0 || c > 55) continue;
      short8 h8 = *(const short8*)(rowp + (size_t)c * 512);
      f32x2 hf[4];
#pragma unroll
      for (int p = 0; p < 4; p++) {
        u32 w = ((const u32*)&h8)[p];
        hf[p] = (f32x2){lo_bf(w), hi_bf(w)};
      }
      int wrow = (di + 1) * 3;
#pragma unroll
      for (int q = 0; q < 4; q++) {
        int dx = j - 1 - q;
        if (dx < -1 || dx > 1) continue;
#pragma unroll
        for (int p = 0; p < 4; p++) acc[q][p] += hf[p] * wf[wrow + dx + 1][p];
      }
    }
  }

  size_t obase = ((size_t)(bb * 3136 + y * 56 + x0)) * 512 + c0;
#pragma unroll
  for (int q = 0; q < 4; q++) {
    short8 ov;
#pragma unroll
    for (int p = 0; p < 4; p++) {
      float g2[2];
#pragma unroll
      for (int e = 0; e < 2; e++) {
        float v = acc[q][p][e];
        float tt = v * v;
        float yn = v * (-2.3022088f - 0.1029434f * tt);
        float ex;
        asm("v_exp_f32 %0, %1" : "=v"(ex) : "v"(yn));
        float den = 1.0f + ex;
        float sg;
        asm("v_rcp_f32 %0, %1" : "=v"(sg) : "v"(den));
        g2[e] = v * sg;
      }
      u32 pk;
      asm("v_cvt_pk_bf16_f32 %0, %1, %2" : "=v"(pk) : "v"(g2[0]), "v"(g2[1]));
      ((u32*)&ov)[p] = pk;
    }
    *(short8*)(Out + obase + (size_t)q * 512) = ov;
  }
}

__global__ __launch_bounds__(256) void fill_sentinel(void* __restrict__ Out,
                                                     const u32* __restrict__ ng, int n) {
  bool f32m = is_f32(ng);
  int t = blockIdx.x * 256 + threadIdx.x;
  if (t >= n) return;
  if (f32m) ((float*)Out)[t] = 12345.0f;
  else      ((u16*)Out)[t]   = f2bf(12345.0f);
}

// ---------------- host launcher ----------------
extern "C" void kernel_launch(void* const* d_in, const int* in_sizes, int n_in,
                              void* d_out, int out_size, void* d_ws, size_t ws_size,
                              hipStream_t stream) {
  (void)in_sizes; (void)n_in;
  const u32* ng = (const u32*)d_in[3];

  const size_t o_X   = 0;                // bf16 X [50176][128]
  const size_t o_H   = 25690112;
  const size_t o_R   = o_H + 12845056;
  const size_t o_Q   = o_R;
  const size_t o_O   = o_R + 12845056;
  const size_t o_Xt  = o_R + 25690112;
  const size_t o_H2C = o_R;
  const size_t o_H2  = o_R + 51380224;   // fc1 out; PS split-K partials alias here
  const size_t o_XSN = o_H2 + 51380224;  // bf16 [3136][128]
  const size_t o_KB  = o_XSN + 802816;
  const size_t o_VT  = o_KB + 802816;    // bf16 VT [2048][224] = 917,504
  const size_t o_M2  = o_VT + 917504;
  const size_t o_AR  = o_M2 + 2809856;
  const size_t NEED  = o_AR + (size_t)ARENA_N * 2;

  if (ws_size < NEED) {
    fill_sentinel<<<(out_size + 255) / 256, 256, 0, stream>>>(d_out, ng, out_size);
    return;
  }

  char* ws = (char*)d_ws;
  u16* Xb   = (u16*)(ws + o_X);
  u16* H    = (u16*)(ws + o_H);
  u16* Qb   = (u16*)(ws + o_Q);
  u16* Ob   = (u16*)(ws + o_O);
  u16* Xt   = (u16*)(ws + o_Xt);
  u16* H2C  = (u16*)(ws + o_H2C);
  u16* H2   = (u16*)(ws + o_H2);
  float* PS = (float*)(ws + o_H2);
  u16* XSN  = (u16*)(ws + o_XSN);
  u16* Kb   = (u16*)(ws + o_KB);
  u16* VT   = (u16*)(ws + o_VT);
  u32* MSK2 = (u32*)(ws + o_M2);
  u16* AR   = (u16*)(ws + o_AR);

  PtrTab tab;
  for (int j = 0; j < 20; j++) tab.p[j] = d_in[j + 1];
  convert_params<<<(ARENA_N + VT_WORDS + 255) / 256, 256, 0, stream>>>(tab, AR, (u32*)VT);

  u16* ACW  = AR + 0;      u16* ACB  = AR + 32768;
  u16* AN1G = AR + 32896;  u16* AN1B = AR + 33152;
  u16* AQW  = AR + 33408;  u16* AKVW = AR + 66176;
  u16* ASRW = AR + 131712; u16* ASRB = AR + 656000;
  u16* ASNG = AR + 656256; u16* ASNB = AR + 656512;
  u16* APW  = AR + 656768; u16* APB  = AR + 689536;
  u16* AN2G = AR + 689792; u16* AN2B = AR + 690048;
  u16* AF1W = AR + 690304; u16* AF1B = AR + 821376;
  u16* ADWW = AR + 822400; u16* ADWB = AR + 831616;
  u16* AF2W = AR + 832640; u16* AF2B = AR + 963712;

  transpose_in<<<dim3(49, 4, 16), 256, 0, stream>>>(d_in[0], ng, Xt);
  // concat + LN1_0 + fused q (AQW block 0) -> Xb, H, Qb
  gemm_n128<<<dim3(1, 784), 256, 0, stream>>>(Xt, ACW, ACB, Xb, nullptr,
                                              AN1G, AN1B, H, AQW, Qb,
                                              50176, 256, 4);

  for (int i = 0; i < 2; i++) {
    u32 fk0, fk1;
    threefry(0u, 42u, 0u, (u32)i, &fk0, &fk1);

    // SR conv: split-K GEMM gathering A directly from H (permuted-K weights)
    gemm_splitk<<<dim3(1, 25, 16), 256, 0, stream>>>(H, ASRW + i * 262144, PS,
                                                     3136, 128, 2048);
    mask_gen2<<<1372, 256, 0, stream>>>(MSK2, fk0, fk1);
    splitk_reduce_ln<<<1568, 256, 0, stream>>>(PS, ASRB + i * 128,
                                               ASNG + i * 128, ASNB + i * 128, XSN);

    // kv: m-tile = blockIdx.x (25), n-tile = blockIdx.y (2)
    gemm_tiled<<<dim3(25, 2), 256, 0, stream>>>(XSN, AKVW + i * 32768, nullptr,
                                                Kb, VT, 3136, 256, 128, 3);
    attn_kernel<<<1568, 256, 0, stream>>>(Qb, Kb, VT, MSK2, Ob);
    // proj + LN2_i
    gemm_n128<<<dim3(1, 784), 256, 0, stream>>>(Ob, APW + i * 16384, APB + i * 128,
                                                Xb, nullptr,
                                                AN2G + i * 128, AN2B + i * 128, H,
                                                nullptr, nullptr, 50176, 128, 5);
    // fc1: m-tile = blockIdx.x (392), n-tile = blockIdx.y (4)
    gemm_tiled<<<dim3(392, 4), 256, 0, stream>>>(H, AF1W + i * 65536, AF1B + i * 512,
                                                 H2, nullptr,
                                                 50176, 512, 128, 0);
    dwconv_gelu<<<3136, 256, 0, stream>>>(H2, ADWW + i * 4608, ADWB + i * 512, H2C);
    if (i == 0) {
      // fc2 + LN1_1 + fused q (AQW block 1) -> Xb, H, Qb
      gemm_n128<<<dim3(1, 784), 256, 0, stream>>>(H2C, AF2W, AF2B, Xb, nullptr,
                                                  AN1G + 128, AN1B + 128, H,
                                                  AQW + 16384, Qb, 50176, 512, 5);
    } else {
      gemm_n128<<<dim3(1, 784), 256, 0, stream>>>(H2C, AF2W + 65536, AF2B + 128,
                                                  Xb, nullptr, nullptr, nullptr, nullptr,
                                                  nullptr, nullptr, 50176, 512, 2);
    }
  }

  transpose_out<<<dim3(49, 2, 16), 256, 0, stream>>>(Xb, ng, d_out);
}

// Round 28
// 409.981 us; speedup vs baseline: 1.3597x; 1.3597x over previous
//
#include <hip/hip_runtime.h>
#include <stdint.h>

typedef __attribute__((ext_vector_type(8))) short short8;
typedef __attribute__((ext_vector_type(4))) float f32x4;
typedef __attribute__((ext_vector_type(2))) float f32x2;
typedef unsigned short u16;
typedef uint32_t u32;
typedef unsigned long long u64;

// ---------------- threefry2x32-20 (JAX-compatible) ----------------
__host__ __device__ static inline void threefry(u32 k0, u32 k1, u32 x0, u32 x1,
                                                u32* o0, u32* o1) {
  u32 ks2 = k0 ^ k1 ^ 0x1BD11BDAu;
  x0 += k0; x1 += k1;
#define TF_RR(r) { x0 += x1; x1 = (x1 << (r)) | (x1 >> (32 - (r))); x1 ^= x0; }
  TF_RR(13) TF_RR(15) TF_RR(26) TF_RR(6)
  x0 += k1;  x1 += ks2 + 1u;
  TF_RR(17) TF_RR(29) TF_RR(16) TF_RR(24)
  x0 += ks2; x1 += k0 + 2u;
  TF_RR(13) TF_RR(15) TF_RR(26) TF_RR(6)
  x0 += k0;  x1 += k1 + 3u;
  TF_RR(17) TF_RR(29) TF_RR(16) TF_RR(24)
  x0 += k1;  x1 += ks2 + 4u;
  TF_RR(13) TF_RR(15) TF_RR(26) TF_RR(6)
  x0 += ks2; x1 += k0 + 5u;
#undef TF_RR
  *o0 = x0; *o1 = x1;
}

__device__ static inline float bf2f(u16 u) {
  union { u32 i; float f; } v; v.i = ((u32)u) << 16; return v.f;
}
__device__ static inline u16 f2bf(float f) {
  union { float f; u32 i; } v; v.f = f;
  u32 x = v.i;
  return (u16)((x + 0x7FFFu + ((x >> 16) & 1u)) >> 16);
}
__device__ static inline float lo_bf(u32 w) {
  union { u32 i; float f; } v; v.i = w << 16; return v.f;
}
__device__ static inline float hi_bf(u32 w) {
  union { u32 i; float f; } v; v.i = w & 0xFFFF0000u; return v.f;
}
__device__ static inline bool is_f32(const u32* ng) { return ng[0] == 0x3F800000u; }

// async global->LDS, 16B per lane
typedef const uint32_t __attribute__((address_space(1)))* gas_ptr;
typedef uint32_t __attribute__((address_space(3)))* las_ptr;
__device__ static inline void gld16(const u16* g, u16* l) {
  __builtin_amdgcn_global_load_lds((gas_ptr)(const void*)g, (las_ptr)(void*)l, 16, 0, 0);
}

#define MASK_HALF 9834496u

// ---------------- fused dropkey mask gen -> per-row 7-word records ----------------
__global__ __launch_bounds__(256) void mask_gen2(u32* __restrict__ MSK2, u32 k0, u32 k1) {
  int t = blockIdx.x * 256 + threadIdx.x;
  if (t >= 351232) return;  // 16 bh-halves * 3136 rows * 7 words
  int w = t % 7;
  int rowbh = t / 7;  // bh*3136 + row, bh in [0,16)
  u32 base = (u32)rowbh * 196u + (u32)w * 32u;
  int kmax = 196 - w * 32;
  if (kmax > 32) kmax = 32;
  u32 bits0 = 0, bits1 = 0;
  for (int j = 0; j < kmax; j++) {
    u32 o0, o1;
    threefry(k0, k1, base + (u32)j, base + (u32)j + MASK_HALF, &o0, &o1);
    union { u32 u; float f; } u0, u1;
    u0.u = (o0 >> 9) | 0x3F800000u;
    u1.u = (o1 >> 9) | 0x3F800000u;
    if (u0.f - 1.0f < 0.1f) bits0 |= (1u << j);
    if (u1.f - 1.0f < 0.1f) bits1 |= (1u << j);
  }
  MSK2[(size_t)rowbh * 7 + w] = bits0;
  MSK2[(size_t)(rowbh + 50176) * 7 + w] = bits1;  // bh+16 half
}

// ---------------- param conversion into bf16 arena + VT zeroing ----------------
// sr_w (t==6) is stored with PERMUTED K: dst k' = ij*128+c  <-  src k = c*16+ij.
struct PtrTab { const void* p[20]; };
#define ARENA_N 963968
#define VT_WORDS 229376

__global__ __launch_bounds__(256) void convert_params(PtrTab tab, u16* __restrict__ arena,
                                                      u32* __restrict__ VT) {
  const int cum[21] = {0, 32768, 32896, 33152, 33408, 66176, 131712, 656000, 656256,
                       656512, 656768, 689536, 689792, 690048, 690304, 821376, 822400,
                       831616, 832640, 963712, 963968};
  int idx = blockIdx.x * 256 + threadIdx.x;
  if (idx >= ARENA_N) {
    int v = idx - ARENA_N;
    if (v < VT_WORDS) VT[v] = 0;
    return;
  }
  bool f32m = (((const u32*)tab.p[2])[0] == 0x3F800000u);
  int t = 0;
  while (idx >= cum[t + 1]) t++;
  int local = idx - cum[t];
  if (t == 16) {  // dw_w transposed to [blk][wi][c]
    int blk = local / 4608, r = local - blk * 4608;
    int wi = r >> 9, c = r & 511;
    local = blk * 4608 + c * 9 + wi;
  } else if (t == 6) {  // sr_w: dst (blk, o, k'=ij*128+c) <- src (blk, o, c*16+ij)
    int blk = local / 262144, r = local - blk * 262144;
    int o = r >> 11, kp = r & 2047;
    int ij = kp >> 7, c = kp & 127;
    local = blk * 262144 + o * 2048 + c * 16 + ij;
  }
  u16 v;
  if (f32m) v = f2bf(((const float*)tab.p[t])[local]);
  else      v = ((const u16*)tab.p[t])[local];
  arena[idx] = v;
}

// ---------------- input transpose ----------------
__global__ __launch_bounds__(256) void transpose_in(const void* __restrict__ Xin,
                                                    const u32* __restrict__ ng,
                                                    u16* __restrict__ Xt) {
  bool f32m = is_f32(ng);
  __shared__ u16 tile[64][65];
  int n0 = blockIdx.x * 64, c0 = blockIdx.y * 64, b = blockIdx.z;
  int tx = threadIdx.x & 63, ty = threadIdx.x >> 6;
  if (f32m) {
    const float* src = (const float*)Xin + (size_t)b * 256 * 3136;
#pragma unroll
    for (int i = 0; i < 16; i++) {
      int cl = i * 4 + ty;
      tile[cl][tx] = f2bf(src[(size_t)(c0 + cl) * 3136 + n0 + tx]);
    }
  } else {
    const u16* src = (const u16*)Xin + (size_t)b * 256 * 3136;
#pragma unroll
    for (int i = 0; i < 16; i++) {
      int cl = i * 4 + ty;
      tile[cl][tx] = src[(size_t)(c0 + cl) * 3136 + n0 + tx];
    }
  }
  __syncthreads();
  u16* dst = Xt + (size_t)b * 3136 * 256;
#pragma unroll
  for (int i = 0; i < 16; i++) {
    int nl = i * 4 + ty;
    dst[(size_t)(n0 + nl) * 256 + c0 + tx] = tile[tx][nl];
  }
}

// ---------------- output transpose: X bf16 [b][3136][128] -> out [b][128][3136] --------
__global__ __launch_bounds__(256) void transpose_out(const u16* __restrict__ X,
                                                     const u32* __restrict__ ng,
                                                     void* __restrict__ Out) {
  bool f32m = is_f32(ng);
  __shared__ u16 tile[64][65];
  int n0 = blockIdx.x * 64, d0 = blockIdx.y * 64, b = blockIdx.z;
  int tx = threadIdx.x & 63, ty = threadIdx.x >> 6;
#pragma unroll
  for (int i = 0; i < 16; i++) {
    int nl = i * 4 + ty;
    tile[nl][tx] = X[((size_t)b * 3136 + n0 + nl) * 128 + d0 + tx];
  }
  __syncthreads();
#pragma unroll
  for (int i = 0; i < 16; i++) {
    int dl = i * 4 + ty;
    size_t o = ((size_t)b * 128 + d0 + dl) * 3136 + n0 + tx;
    if (f32m) ((float*)Out)[o] = bf2f(tile[tx][dl]);
    else      ((u16*)Out)[o]   = tile[tx][dl];
  }
}

// ---------------- tiled MFMA GEMM (m-tile = blockIdx.x, n-tile = blockIdx.y) -----------
__global__ __launch_bounds__(256) __attribute__((amdgpu_waves_per_eu(2, 4)))
void gemm_tiled(const u16* __restrict__ A,
                const u16* __restrict__ W,
                const u16* __restrict__ bias,
                u16* __restrict__ outB,
                u16* __restrict__ outVT,
                int M, int N, int K, int mode) {
  __shared__ __align__(16) u16 smem[17408];  // staging 32KB / C-tile [128][136]
  u16* AlsP = smem;
  u16* BlsP = smem + 8192;
  int n0 = blockIdx.y * 128, m0 = blockIdx.x * 128;
  int tid = threadIdx.x, wv = tid >> 6, lane = tid & 63;
  int wr = wv >> 1, wc = wv & 1;
  int l15 = lane & 15, hh = lane >> 4, lk = hh * 8;
  int srow = wv * 32 + (lane >> 2);
  int scol = (lane & 3) * 8;

  f32x4 acc[4][4];
#pragma unroll
  for (int m = 0; m < 4; m++)
#pragma unroll
    for (int n = 0; n < 4; n++) acc[m][n] = (f32x4){0.f, 0.f, 0.f, 0.f};

#define STAGE(buf, k0)                                                          \
  {                                                                             \
    _Pragma("unroll") for (int i = 0; i < 2; i++) {                             \
      int ar = m0 + srow + i * 16;                                              \
      if (ar >= M) ar = M - 1;                                                  \
      gld16(A + (size_t)ar * K + (k0) + scol,                                   \
            AlsP + (buf) * 4096 + (wv * 32 + i * 16) * 32);                     \
      int br = n0 + srow + i * 16;                                              \
      gld16(W + (size_t)br * K + (k0) + scol,                                   \
            BlsP + (buf) * 4096 + (wv * 32 + i * 16) * 32);                     \
    }                                                                           \
  }

  int nt = K >> 5;
  STAGE(0, 0);
  int cur = 0;
  for (int t = 0; t < nt; t++) {
    __syncthreads();
    if (t + 1 < nt) STAGE(cur ^ 1, (t + 1) * 32);
    short8 af[4], bf[4];
#pragma unroll
    for (int m = 0; m < 4; m++)
      af[m] = *(const short8*)(AlsP + cur * 4096 + (wr * 64 + m * 16 + l15) * 32 + lk);
#pragma unroll
    for (int n = 0; n < 4; n++)
      bf[n] = *(const short8*)(BlsP + cur * 4096 + (wc * 64 + n * 16 + l15) * 32 + lk);
#pragma unroll
    for (int m = 0; m < 4; m++)
#pragma unroll
      for (int n = 0; n < 4; n++)
        acc[m][n] = __builtin_amdgcn_mfma_f32_16x16x32_bf16(af[m], bf[n], acc[m][n], 0, 0, 0);
    cur ^= 1;
  }
#undef STAGE

  if (mode == 0) {
    __syncthreads();
#pragma unroll
    for (int n = 0; n < 4; n++) {
      int col = wc * 64 + n * 16 + l15;
      float bv = bias ? bf2f(bias[n0 + col]) : 0.0f;
#pragma unroll
      for (int m = 0; m < 4; m++) {
        int rbase = wr * 64 + m * 16 + hh * 4;
#pragma unroll
        for (int r = 0; r < 4; r++)
          smem[(rbase + r) * 136 + col] = f2bf(acc[m][n][r] + bv);
      }
    }
    __syncthreads();
#pragma unroll
    for (int p = 0; p < 8; p++) {
      int row = p * 16 + (tid >> 4);
      int colb = (tid & 15) * 8;
      int grow = m0 + row;
      if (grow < M) {
        short8 v = *(const short8*)&smem[row * 136 + colb];
        *(short8*)(outB + (size_t)grow * N + n0 + colb) = v;
      }
    }
    return;
  }

  // mode 3 (kv)
#pragma unroll
  for (int n = 0; n < 4; n++) {
    int col = n0 + wc * 64 + n * 16 + l15;
#pragma unroll
    for (int m = 0; m < 4; m++) {
      int rbase = m0 + wr * 64 + m * 16 + hh * 4;
#pragma unroll
      for (int r = 0; r < 4; r++) {
        int row = rbase + r;
        if (row < M) {
          float v = acc[m][n][r];
          if (col < 128) outB[(size_t)row * 128 + col] = f2bf(v);
          else {
            int hd = (col - 128) >> 6, d = (col - 128) & 63;
            int b = row / 196, key = row - b * 196;
            outVT[(size_t)((b * 2 + hd) * 64 + d) * 224 + key] = f2bf(v);
          }
        }
      }
    }
  }
}

// ---------------- BM=64 N=128 GEMM (concat/proj/fc2[,+q]) -- 784 blocks ----------------
__global__ __launch_bounds__(256) __attribute__((amdgpu_waves_per_eu(2, 4)))
void gemm_n128(const u16* __restrict__ A,
               const u16* __restrict__ W,
               const u16* __restrict__ bias,
               u16* __restrict__ Xb,
               u16* __restrict__ outB,
               const u16* __restrict__ lnG,
               const u16* __restrict__ lnB,
               u16* __restrict__ outH,
               const u16* __restrict__ qW,
               u16* __restrict__ outQ,
               int M, int K, int mode) {
  __shared__ __align__(16) u16 smem[12288];  // A[2][2048]+B[2][4096]=24KB / C [64][136]
  __shared__ float sumsA[64][4];
  __shared__ float sumsB[64][4];
  u16* Als = smem;           // buf*2048
  u16* Bls = smem + 4096;    // buf*4096
  int m0 = blockIdx.y * 64;
  int tid = threadIdx.x, wv = tid >> 6, lane = tid & 63;
  int l15 = lane & 15, hq = lane >> 4, lk = hq * 8;
  int scol = (lane & 3) * 8;

  f32x4 acc[4][2];
#pragma unroll
  for (int m = 0; m < 4; m++)
#pragma unroll
    for (int n = 0; n < 2; n++) acc[m][n] = (f32x4){0.f, 0.f, 0.f, 0.f};

#define STAGE(buf, k0)                                                          \
  {                                                                             \
    int ar = m0 + wv * 16 + (lane >> 2);                                        \
    if (ar >= M) ar = M - 1;                                                    \
    gld16(A + (size_t)ar * K + (k0) + scol, Als + (buf) * 2048 + wv * 512);     \
    _Pragma("unroll") for (int i = 0; i < 2; i++) {                             \
      int br = wv * 32 + i * 16 + (lane >> 2);                                  \
      gld16(W + (size_t)br * K + (k0) + scol,                                   \
            Bls + (buf) * 4096 + wv * 1024 + i * 512);                          \
    }                                                                           \
  }

  int nt = K >> 5;
  STAGE(0, 0);
  int cur = 0;
  for (int t = 0; t < nt; t++) {
    __syncthreads();
    if (t + 1 < nt) STAGE(cur ^ 1, (t + 1) * 32);
    short8 af[4], bf[2];
#pragma unroll
    for (int m = 0; m < 4; m++)
      af[m] = *(const short8*)(Als + cur * 2048 + (m * 16 + l15) * 32 + lk);
#pragma unroll
    for (int n = 0; n < 2; n++)
      bf[n] = *(const short8*)(Bls + cur * 4096 + (wv * 32 + n * 16 + l15) * 32 + lk);
#pragma unroll
    for (int m = 0; m < 4; m++)
#pragma unroll
      for (int n = 0; n < 2; n++)
        acc[m][n] = __builtin_amdgcn_mfma_f32_16x16x32_bf16(af[m], bf[n], acc[m][n], 0, 0, 0);
    cur ^= 1;
  }
#undef STAGE

  if (mode == 2) {
#pragma unroll
    for (int n = 0; n < 2; n++) {
      int col = wv * 32 + n * 16 + l15;
      float bv = bias ? bf2f(bias[col]) : 0.0f;
#pragma unroll
      for (int m = 0; m < 4; m++) {
        int rbase = m0 + m * 16 + hq * 4;
#pragma unroll
        for (int r = 0; r < 4; r++) {
          size_t idx = (size_t)(rbase + r) * 128 + col;
          Xb[idx] = f2bf(bf2f(Xb[idx]) + acc[m][n][r] + bv);
        }
      }
    }
    return;
  }

  if (mode >= 4) {
#pragma unroll
    for (int n = 0; n < 2; n++) {
      int col = wv * 32 + n * 16 + l15;
      float bv = bias ? bf2f(bias[col]) : 0.0f;
#pragma unroll
      for (int m = 0; m < 4; m++) {
        int rbase = m0 + m * 16 + hq * 4;
#pragma unroll
        for (int r = 0; r < 4; r++) {
          size_t idx = (size_t)(rbase + r) * 128 + col;
          float v = acc[m][n][r] + bv;
          if (mode == 5) v += bf2f(Xb[idx]);
          acc[m][n][r] = v;
          Xb[idx] = f2bf(v);
        }
      }
    }
#pragma unroll
    for (int m = 0; m < 4; m++) {
#pragma unroll
      for (int r = 0; r < 4; r++) {
        float a = acc[m][0][r] + acc[m][1][r];
        float b = acc[m][0][r] * acc[m][0][r] + acc[m][1][r] * acc[m][1][r];
#pragma unroll
        for (int d = 1; d < 16; d <<= 1) {
          a += __shfl_xor(a, d);
          b += __shfl_xor(b, d);
        }
        if (l15 == 0) {
          int lrow = m * 16 + hq * 4 + r;
          sumsA[lrow][wv] = a;
          sumsB[lrow][wv] = b;
        }
      }
    }
    __syncthreads();
#pragma unroll
    for (int m = 0; m < 4; m++) {
#pragma unroll
      for (int r = 0; r < 4; r++) {
        int lrow = m * 16 + hq * 4 + r;
        float t1 = sumsA[lrow][0] + sumsA[lrow][1] + sumsA[lrow][2] + sumsA[lrow][3];
        float t2 = sumsB[lrow][0] + sumsB[lrow][1] + sumsB[lrow][2] + sumsB[lrow][3];
        float mean = t1 * 0.0078125f;
        float var = t2 * 0.0078125f - mean * mean;
        float inv = 1.0f / sqrtf(var + 1e-5f);
#pragma unroll
        for (int n = 0; n < 2; n++) {
          int col = wv * 32 + n * 16 + l15;
          float g = bf2f(lnG[col]), bb2 = bf2f(lnB[col]);
          smem[lrow * 136 + col] = f2bf((acc[m][n][r] - mean) * inv * g + bb2);
        }
      }
    }
    __syncthreads();
#pragma unroll
    for (int p = 0; p < 4; p++) {
      int row = p * 16 + (tid >> 4);
      int colb = (tid & 15) * 8;
      short8 v = *(const short8*)&smem[row * 136 + colb];
      *(short8*)(outH + (size_t)(m0 + row) * 128 + colb) = v;
    }

    if (qW) {
#pragma unroll
      for (int m = 0; m < 4; m++)
#pragma unroll
        for (int n = 0; n < 2; n++) acc[m][n] = (f32x4){0.f, 0.f, 0.f, 0.f};
#pragma unroll
      for (int kc = 0; kc < 4; kc++) {
        short8 af[4], bf[2];
#pragma unroll
        for (int m = 0; m < 4; m++)
          af[m] = *(const short8*)&smem[(m * 16 + l15) * 136 + kc * 32 + lk];
#pragma unroll
        for (int n = 0; n < 2; n++)
          bf[n] = *(const short8*)(qW + (size_t)(wv * 32 + n * 16 + l15) * 128 +
                                   kc * 32 + lk);
#pragma unroll
        for (int m = 0; m < 4; m++)
#pragma unroll
          for (int n = 0; n < 2; n++)
            acc[m][n] =
                __builtin_amdgcn_mfma_f32_16x16x32_bf16(af[m], bf[n], acc[m][n], 0, 0, 0);
      }
      __syncthreads();
#pragma unroll
      for (int n = 0; n < 2; n++) {
        int col = wv * 32 + n * 16 + l15;
#pragma unroll
        for (int m = 0; m < 4; m++) {
          int rbase = m * 16 + hq * 4;
#pragma unroll
          for (int r = 0; r < 4; r++)
            smem[(rbase + r) * 136 + col] = f2bf(acc[m][n][r]);
        }
      }
      __syncthreads();
#pragma unroll
      for (int p = 0; p < 4; p++) {
        int row = p * 16 + (tid >> 4);
        int colb = (tid & 15) * 8;
        short8 v = *(const short8*)&smem[row * 136 + colb];
        *(short8*)(outQ + (size_t)(m0 + row) * 128 + colb) = v;
      }
    }
    return;
  }

  // mode 0: bf16 store via LDS-coalesced epilogue
  __syncthreads();
#pragma unroll
  for (int n = 0; n < 2; n++) {
    int col = wv * 32 + n * 16 + l15;
    float bv = bias ? bf2f(bias[col]) : 0.0f;
#pragma unroll
    for (int m = 0; m < 4; m++) {
      int rbase = m * 16 + hq * 4;
#pragma unroll
      for (int r = 0; r < 4; r++)
        smem[(rbase + r) * 136 + col] = f2bf(acc[m][n][r] + bv);
    }
  }
  __syncthreads();
#pragma unroll
  for (int p = 0; p < 4; p++) {
    int row = p * 16 + (tid >> 4);
    int colb = (tid & 15) * 8;
    short8 v = *(const short8*)&smem[row * 136 + colb];
    *(short8*)(outB + (size_t)(m0 + row) * 128 + colb) = v;
  }
}

// ---------------- split-K GEMM for SR conv, direct-from-H gather (no im2col) -----------
// K-order k' = ij*128 + c; A element (row=(b,ph,pw), k') = H[(b*3136+(4ph+i)*56+4pw+j)*128+c]
__global__ __launch_bounds__(256) void gemm_splitk(const u16* __restrict__ Hsrc,
                                                   const u16* __restrict__ W,
                                                   float* __restrict__ PS,
                                                   int M, int N, int K) {
  __shared__ __align__(16) u16 Als[2][4096];
  __shared__ __align__(16) u16 Bls[2][4096];
  int n0 = blockIdx.x * 128, m0 = blockIdx.y * 128, ks = blockIdx.z;
  int tid = threadIdx.x, wv = tid >> 6, lane = tid & 63;
  int wr = wv >> 1, wc = wv & 1;
  int l15 = lane & 15, lk = (lane >> 4) * 8;
  int srow = wv * 32 + (lane >> 2);
  int scol = (lane & 3) * 8;

  f32x4 acc[4][4];
#pragma unroll
  for (int m = 0; m < 4; m++)
#pragma unroll
    for (int n = 0; n < 4; n++) acc[m][n] = (f32x4){0.f, 0.f, 0.f, 0.f};

#define STAGE(buf, k0)                                                          \
  {                                                                             \
    _Pragma("unroll") for (int i = 0; i < 2; i++) {                             \
      int ar = m0 + srow + i * 16;                                              \
      if (ar >= M) ar = M - 1;                                                  \
      int bb = ar / 196, pp = ar - bb * 196;                                    \
      int ph = pp / 14, pw = pp - ph * 14;                                      \
      int kk = (k0) + scol;                                                     \
      int ij = kk >> 7, c = kk & 127;                                           \
      int n2 = (4 * ph + (ij >> 2)) * 56 + 4 * pw + (ij & 3);                   \
      gld16(Hsrc + ((size_t)(bb * 3136 + n2)) * 128 + c,                        \
            &Als[buf][(wv * 32 + i * 16) * 32]);                                \
      int br = n0 + srow + i * 16;                                              \
      gld16(W + (size_t)br * K + (k0) + scol,                                   \
            &Bls[buf][(wv * 32 + i * 16) * 32]);                                \
    }                                                                           \
  }

  int kbeg = ks * 128;
  STAGE(0, kbeg);
  int cur = 0;
  for (int t = 0; t < 4; t++) {
    __syncthreads();
    if (t + 1 < 4) STAGE(cur ^ 1, kbeg + (t + 1) * 32);
    short8 af[4], bf[4];
#pragma unroll
    for (int m = 0; m < 4; m++)
      af[m] = *(const short8*)(&Als[cur][(wr * 64 + m * 16 + l15) * 32 + lk]);
#pragma unroll
    for (int n = 0; n < 4; n++)
      bf[n] = *(const short8*)(&Bls[cur][(wc * 64 + n * 16 + l15) * 32 + lk]);
#pragma unroll
    for (int m = 0; m < 4; m++)
#pragma unroll
      for (int n = 0; n < 4; n++)
        acc[m][n] = __builtin_amdgcn_mfma_f32_16x16x32_bf16(af[m], bf[n], acc[m][n], 0, 0, 0);
    cur ^= 1;
  }
#undef STAGE

  float* myPS = PS + (size_t)ks * M * N;
#pragma unroll
  for (int n = 0; n < 4; n++) {
    int col = n0 + wc * 64 + n * 16 + l15;
#pragma unroll
    for (int m = 0; m < 4; m++) {
      int rbase = m0 + wr * 64 + m * 16 + (lane >> 4) * 4;
#pragma unroll
      for (int r = 0; r < 4; r++) {
        int row = rbase + r;
        if (row < M) myPS[(size_t)row * N + col] = acc[m][n][r];
      }
    }
  }
}

// ---------------- fused split-K reduce + srn LayerNorm -> XSN bf16 ----------------
__global__ __launch_bounds__(256) void splitk_reduce_ln(const float* __restrict__ PS,
                                                        const u16* __restrict__ bias,
                                                        const u16* __restrict__ G,
                                                        const u16* __restrict__ Bi,
                                                        u16* __restrict__ XSN) {
  __shared__ float red[4][2];
  int tid = threadIdx.x;
  int row = blockIdx.x * 2 + (tid >> 7);
  int col = tid & 127;
  int t = row * 128 + col;
  float s = bf2f(bias[col]);
#pragma unroll
  for (int k = 0; k < 16; k++) s += PS[(size_t)k * 401408 + t];
  float s1 = s, s2 = s * s;
#pragma unroll
  for (int d = 1; d < 64; d <<= 1) {
    s1 += __shfl_xor(s1, d);
    s2 += __shfl_xor(s2, d);
  }
  int wv = tid >> 6;
  if ((tid & 63) == 0) { red[wv][0] = s1; red[wv][1] = s2; }
  __syncthreads();
  int other = wv ^ 1;
  float t1 = red[wv][0] + red[other][0];
  float t2 = red[wv][1] + red[other][1];
  float mean = t1 * 0.0078125f;
  float var = t2 * 0.0078125f - mean * mean;
  float inv = 1.0f / sqrtf(var + 1e-5f);
  XSN[t] = f2bf((s - mean) * inv * bf2f(G[col]) + bf2f(Bi[col]));
}

// ---------------- fused SR attention v8: K staged in LDS (padded), v5 softmax -----------
__global__ __launch_bounds__(256) __attribute__((amdgpu_waves_per_eu(2, 4)))
void attn_kernel(const u16* __restrict__ Q,
                 const u16* __restrict__ Kb,
                 const u16* __restrict__ VT,
                 const u32* __restrict__ M2,
                 u16* __restrict__ O) {
  __shared__ __align__(16) u16 smA[14848];  // K [196][68] (13328) / P [64][232] (14848)
  int t = blockIdx.x;
  int tp = (t & 7) * 196 + (t >> 3);  // XCD-contiguous bh spans
  int bh = tp / 49, qt = tp - bh * 49;
  int b = bh >> 1, hd = bh & 1;
  int q0 = qt * 64;
  int tid = threadIdx.x;

  int wv = tid >> 6, lane = tid & 63;
  int l15 = lane & 15, h = lane >> 4, lk = h * 8;

  {
    const u16* ksrc = Kb + (size_t)b * 196 * 128 + hd * 64;
    for (int idx = tid; idx < 1568; idx += 256) {
      int row = idx >> 3, ch = idx & 7;
      short8 v = *(const short8*)(ksrc + (size_t)row * 128 + ch * 8);
      *(short8*)&smA[row * 68 + ch * 8] = v;
    }
  }

  const u16* qp = Q + ((size_t)(b * 3136 + q0 + wv * 16 + l15) * 128) + hd * 64 + lk;
  short8 aq0 = *(const short8*)(qp);
  short8 aq1 = *(const short8*)(qp + 32);
  int rowg = q0 + wv * 16 + h * 4;

  u32 mwv[4][7];
  const u32* mwbase = M2 + (size_t)(bh * 3136 + rowg) * 7;
#pragma unroll
  for (int r = 0; r < 4; r++)
#pragma unroll
    for (int w = 0; w < 7; w++) mwv[r][w] = mwbase[r * 7 + w];

  __syncthreads();  // K staged

  float sarr[13][4];
#pragma unroll
  for (int cc = 0; cc < 13; cc++) {
    int key = cc * 16 + l15;
    int keyc = key > 195 ? 195 : key;
    short8 kb0 = *(const short8*)&smA[keyc * 68 + lk];
    short8 kb1 = *(const short8*)&smA[keyc * 68 + 32 + lk];
    f32x4 s = {0.f, 0.f, 0.f, 0.f};
    s = __builtin_amdgcn_mfma_f32_16x16x32_bf16(aq0, kb0, s, 0, 0, 0);
    s = __builtin_amdgcn_mfma_f32_16x16x32_bf16(aq1, kb1, s, 0, 0, 0);
#pragma unroll
    for (int r = 0; r < 4; r++) sarr[cc][r] = s[r] * 0.125f;
  }

#pragma unroll
  for (int cc = 0; cc < 13; cc++) {
    bool keyok = (cc * 16 + l15) < 196;
    int pos = (cc & 3) * 16 + l15;
#pragma unroll
    for (int r = 0; r < 4; r++) {
      u64 mm = (cc < 4) ? ((u64)mwv[r][0] | ((u64)mwv[r][1] << 32))
             : (cc < 8) ? ((u64)mwv[r][2] | ((u64)mwv[r][3] << 32))
             : (cc < 12) ? ((u64)mwv[r][4] | ((u64)mwv[r][5] << 32))
                         : ((u64)mwv[r][6]);
      bool drop = (mm >> pos) & 1ull;
      if (!keyok || drop) sarr[cc][r] = -3.0e38f;
    }
  }

  float mx[4] = {sarr[0][0], sarr[0][1], sarr[0][2], sarr[0][3]};
#pragma unroll
  for (int cc = 1; cc < 13; cc++)
#pragma unroll
    for (int r = 0; r < 4; r++) mx[r] = fmaxf(mx[r], sarr[cc][r]);
#pragma unroll
  for (int d = 1; d < 16; d <<= 1)
#pragma unroll
    for (int r = 0; r < 4; r++) mx[r] = fmaxf(mx[r], __shfl_xor(mx[r], d));
  float sm[4] = {0.f, 0.f, 0.f, 0.f};
#pragma unroll
  for (int cc = 0; cc < 13; cc++)
#pragma unroll
    for (int r = 0; r < 4; r++) {
      float p = __expf(sarr[cc][r] - mx[r]);
      sarr[cc][r] = p;
      sm[r] += p;
    }
#pragma unroll
  for (int d = 1; d < 16; d <<= 1)
#pragma unroll
    for (int r = 0; r < 4; r++) sm[r] += __shfl_xor(sm[r], d);
  float inv[4];
#pragma unroll
  for (int r = 0; r < 4; r++)
    asm("v_rcp_f32 %0, %1" : "=v"(inv[r]) : "v"(sm[r]));

  __syncthreads();  // K region -> P

#pragma unroll
  for (int cc = 0; cc < 13; cc++)
#pragma unroll
    for (int r = 0; r < 4; r++)
      smA[(wv * 16 + h * 4 + r) * 232 + cc * 16 + l15] = f2bf(sarr[cc][r] * inv[r]);
#pragma unroll
  for (int rj = 0; rj < 4; rj++) smA[(wv * 16 + l15) * 232 + 208 + h * 4 + rj] = 0;

  const u16* vbase = VT + (size_t)(bh * 64) * 224;
  short8 vw[4];
#pragma unroll
  for (int i = 0; i < 4; i++) {
    vw[i] = *(const short8*)(vbase + (size_t)(0 * 16 + l15) * 224 + i * 32 + lk);
  }
#pragma unroll
  for (int dc = 0; dc < 4; dc++) {
    f32x4 oa = {0.f, 0.f, 0.f, 0.f};
#pragma unroll
    for (int kc = 0; kc < 7; kc++) {
      int i = dc * 7 + kc;
      short8 bv = vw[i & 3];
      if (i + 4 < 28) {
        int i2 = i + 4;
        int dc2 = i2 / 7, kc2 = i2 - dc2 * 7;
        vw[i & 3] =
            *(const short8*)(vbase + (size_t)(dc2 * 16 + l15) * 224 + kc2 * 32 + lk);
      }
      short8 a = *(const short8*)&smA[(wv * 16 + l15) * 232 + kc * 32 + lk];
      oa = __builtin_amdgcn_mfma_f32_16x16x32_bf16(a, bv, oa, 0, 0, 0);
    }
#pragma unroll
    for (int r = 0; r < 4; r++) {
      O[((size_t)(b * 3136 + rowg + r) * 128) + hd * 64 + dc * 16 + l15] = f2bf(oa[r]);
    }
  }
}

// ---------------- depthwise 3x3 + bias + exp2-sigmoid GELU, cvt_pk output ---------------
__global__ __launch_bounds__(256) __attribute__((amdgpu_waves_per_eu(2, 4)))
void dwconv_gelu(const u16* __restrict__ H2,
                 const u16* __restrict__ Wdw,
                 const u16* __restrict__ Bdw,
                 u16* __restrict__ Out) {
  int tid = threadIdx.x;
  int wv = tid >> 6, lane = tid & 63;
  int sb = blockIdx.x;                          // 3136 blocks
  int wg = (sb & 7) * 392 + (sb >> 3);          // XCD-contiguous remap
  int strip = wg * 4 + wv;                      // < 12544
  int bb = strip / 784;
  int s = strip - bb * 784;
  int y = s / 14, x0 = (s - y * 14) * 4;
  int c0 = lane * 8;

  f32x2 wf[9][4];
#pragma unroll
  for (int t9 = 0; t9 < 9; t9++) {
    short8 w8 = *(const short8*)(Wdw + t9 * 512 + c0);
#pragma unroll
    for (int p = 0; p < 4; p++) {
      u32 w = ((const u32*)&w8)[p];
      wf[t9][p] = (f32x2){lo_bf(w), hi_bf(w)};
    }
  }
  f32x2 acc[4][4];
  {
    short8 b8 = *(const short8*)(Bdw + c0);
#pragma unroll
    for (int p = 0; p < 4; p++) {
      u32 w = ((const u32*)&b8)[p];
      f32x2 bv = {lo_bf(w), hi_bf(w)};
#pragma unroll
      for (int q = 0; q < 4; q++) acc[q][p] = bv;
    }
  }

  const u16* base = H2 + ((size_t)bb * 3136) * 512 + c0;
#pragma unroll
  for (int di = -1; di <= 1; di++) {
    int y2 = y + di;
    if (y2 < 0 || y2 >= 56) continue;
    const u16* rowp = base + (size_t)(y2 * 56) * 512;
#pragma unroll
    for (int j = 0; j < 6; j++) {
      int c = x0 - 1 + j;
      if (c < 0 || c > 55) continue;
      short8 h8 = *(const short8*)(rowp + (size_t)c * 512);
      f32x2 hf[4];
#pragma unroll
      for (int p = 0; p < 4; p++) {
        u32 w = ((const u32*)&h8)[p];
        hf[p] = (f32x2){lo_bf(w), hi_bf(w)};
      }
      int wrow = (di + 1) * 3;
#pragma unroll
      for (int q = 0; q < 4; q++) {
        int dx = j - 1 - q;
        if (dx < -1 || dx > 1) continue;
#pragma unroll
        for (int p = 0; p < 4; p++) acc[q][p] += hf[p] * wf[wrow + dx + 1][p];
      }
    }
  }

  size_t obase = ((size_t)(bb * 3136 + y * 56 + x0)) * 512 + c0;
#pragma unroll
  for (int q = 0; q < 4; q++) {
    short8 ov;
#pragma unroll
    for (int p = 0; p < 4; p++) {
      float g2[2];
#pragma unroll
      for (int e = 0; e < 2; e++) {
        float v = acc[q][p][e];
        float tt = v * v;
        float yn = v * (-2.3022088f - 0.1029434f * tt);
        float ex;
        asm("v_exp_f32 %0, %1" : "=v"(ex) : "v"(yn));
        float den = 1.0f + ex;
        float sg;
        asm("v_rcp_f32 %0, %1" : "=v"(sg) : "v"(den));
        g2[e] = v * sg;
      }
      u32 pk;
      asm("v_cvt_pk_bf16_f32 %0, %1, %2" : "=v"(pk) : "v"(g2[0]), "v"(g2[1]));
      ((u32*)&ov)[p] = pk;
    }
    *(short8*)(Out + obase + (size_t)q * 512) = ov;
  }
}

__global__ __launch_bounds__(256) void fill_sentinel(void* __restrict__ Out,
                                                     const u32* __restrict__ ng, int n) {
  bool f32m = is_f32(ng);
  int t = blockIdx.x * 256 + threadIdx.x;
  if (t >= n) return;
  if (f32m) ((float*)Out)[t] = 12345.0f;
  else      ((u16*)Out)[t]   = f2bf(12345.0f);
}

// ---------------- host launcher ----------------
extern "C" void kernel_launch(void* const* d_in, const int* in_sizes, int n_in,
                              void* d_out, int out_size, void* d_ws, size_t ws_size,
                              hipStream_t stream) {
  (void)in_sizes; (void)n_in;
  const u32* ng = (const u32*)d_in[3];

  const size_t o_X   = 0;                // bf16 X [50176][128]
  const size_t o_H   = 25690112;
  const size_t o_R   = o_H + 12845056;
  const size_t o_Q   = o_R;
  const size_t o_O   = o_R + 12845056;
  const size_t o_Xt  = o_R + 25690112;
  const size_t o_H2C = o_R;
  const size_t o_H2  = o_R + 51380224;   // fc1 out; PS split-K partials alias here
  const size_t o_XSN = o_H2 + 51380224;  // bf16 [3136][128]
  const size_t o_KB  = o_XSN + 802816;
  const size_t o_VT  = o_KB + 802816;    // bf16 VT [2048][224] = 917,504
  const size_t o_M2  = o_VT + 917504;
  const size_t o_AR  = o_M2 + 2809856;
  const size_t NEED  = o_AR + (size_t)ARENA_N * 2;

  if (ws_size < NEED) {
    fill_sentinel<<<(out_size + 255) / 256, 256, 0, stream>>>(d_out, ng, out_size);
    return;
  }

  char* ws = (char*)d_ws;
  u16* Xb   = (u16*)(ws + o_X);
  u16* H    = (u16*)(ws + o_H);
  u16* Qb   = (u16*)(ws + o_Q);
  u16* Ob   = (u16*)(ws + o_O);
  u16* Xt   = (u16*)(ws + o_Xt);
  u16* H2C  = (u16*)(ws + o_H2C);
  u16* H2   = (u16*)(ws + o_H2);
  float* PS = (float*)(ws + o_H2);
  u16* XSN  = (u16*)(ws + o_XSN);
  u16* Kb   = (u16*)(ws + o_KB);
  u16* VT   = (u16*)(ws + o_VT);
  u32* MSK2 = (u32*)(ws + o_M2);
  u16* AR   = (u16*)(ws + o_AR);

  PtrTab tab;
  for (int j = 0; j < 20; j++) tab.p[j] = d_in[j + 1];
  convert_params<<<(ARENA_N + VT_WORDS + 255) / 256, 256, 0, stream>>>(tab, AR, (u32*)VT);

  u16* ACW  = AR + 0;      u16* ACB  = AR + 32768;
  u16* AN1G = AR + 32896;  u16* AN1B = AR + 33152;
  u16* AQW  = AR + 33408;  u16* AKVW = AR + 66176;
  u16* ASRW = AR + 131712; u16* ASRB = AR + 656000;
  u16* ASNG = AR + 656256; u16* ASNB = AR + 656512;
  u16* APW  = AR + 656768; u16* APB  = AR + 689536;
  u16* AN2G = AR + 689792; u16* AN2B = AR + 690048;
  u16* AF1W = AR + 690304; u16* AF1B = AR + 821376;
  u16* ADWW = AR + 822400; u16* ADWB = AR + 831616;
  u16* AF2W = AR + 832640; u16* AF2B = AR + 963712;

  transpose_in<<<dim3(49, 4, 16), 256, 0, stream>>>(d_in[0], ng, Xt);
  // concat + LN1_0 + fused q (AQW block 0) -> Xb, H, Qb
  gemm_n128<<<dim3(1, 784), 256, 0, stream>>>(Xt, ACW, ACB, Xb, nullptr,
                                              AN1G, AN1B, H, AQW, Qb,
                                              50176, 256, 4);

  for (int i = 0; i < 2; i++) {
    u32 fk0, fk1;
    threefry(0u, 42u, 0u, (u32)i, &fk0, &fk1);

    // SR conv: split-K GEMM gathering A directly from H (permuted-K weights)
    gemm_splitk<<<dim3(1, 25, 16), 256, 0, stream>>>(H, ASRW + i * 262144, PS,
                                                     3136, 128, 2048);
    mask_gen2<<<1372, 256, 0, stream>>>(MSK2, fk0, fk1);
    splitk_reduce_ln<<<1568, 256, 0, stream>>>(PS, ASRB + i * 128,
                                               ASNG + i * 128, ASNB + i * 128, XSN);

    // kv: m-tile = blockIdx.x (25), n-tile = blockIdx.y (2)
    gemm_tiled<<<dim3(25, 2), 256, 0, stream>>>(XSN, AKVW + i * 32768, nullptr,
                                                Kb, VT, 3136, 256, 128, 3);
    attn_kernel<<<1568, 256, 0, stream>>>(Qb, Kb, VT, MSK2, Ob);
    // proj + LN2_i
    gemm_n128<<<dim3(1, 784), 256, 0, stream>>>(Ob, APW + i * 16384, APB + i * 128,
                                                Xb, nullptr,
                                                AN2G + i * 128, AN2B + i * 128, H,
                                                nullptr, nullptr, 50176, 128, 5);
    // fc1: m-tile = blockIdx.x (392), n-tile = blockIdx.y (4)
    gemm_tiled<<<dim3(392, 4), 256, 0, stream>>>(H, AF1W + i * 65536, AF1B + i * 512,
                                                 H2, nullptr,
                                                 50176, 512, 128, 0);
    dwconv_gelu<<<3136, 256, 0, stream>>>(H2, ADWW + i * 4608, ADWB + i * 512, H2C);
    if (i == 0) {
      // fc2 + LN1_1 + fused q (AQW block 1) -> Xb, H, Qb
      gemm_n128<<<dim3(1, 784), 256, 0, stream>>>(H2C, AF2W, AF2B, Xb, nullptr,
                                                  AN1G + 128, AN1B + 128, H,
                                                  AQW + 16384, Qb, 50176, 512, 5);
    } else {
      gemm_n128<<<dim3(1, 784), 256, 0, stream>>>(H2C, AF2W + 65536, AF2B + 128,
                                                  Xb, nullptr, nullptr, nullptr, nullptr,
                                                  nullptr, nullptr, 50176, 512, 2);
    }
  }

  transpose_out<<<dim3(49, 2, 16), 256, 0, stream>>>(Xb, ng, d_out);
}